// Round 15
// baseline (300.280 us; speedup 1.0000x reference)
//
#include <hip/hip_runtime.h>
#include <hip/hip_bf16.h>
#include <math.h>

#define BATCH 2
#define NPT   8192
#define DIMC  128
#define NH    4
#define KNN_K 16
#define HID   32
#define BN    (BATCH*NPT)   // 16384

// ===========================================================================
// KNN via exact Z-SLAB pruned scan (round-14).
// r13 full scan: 107 µs, issue-bound, 8192 candidates/query. r9-r11 3-D grid
// failed on SERIAL PER-CELL latency rounds, not on pruning principle. Slabs
// fix the structure: points sorted by z-slab (32 x 0.25 over [-4,4], clamp);
// a query's [cz-2,cz+2] window is ONE CONTIGUOUS coalesced range (~1280 pts,
// 20 chunks). Exact termination: unseen points lie outside the covered
// z-interval; per-side margins (minus 1e-5 slop; clamped outliers provably
// outside) lower-bound d2. Widen tighter side one contiguous slab at a time
// until min-margin^2 > tau or everything scanned (degenerates to full scan
// for far outliers — still coalesced).
// Distance: pts4=(2x,2y,2z,sq), d2=(qsq+sq)-dot2 — bit-matches numpy's
// sq_i+sq_j-2*dot (r9-r11-verified). Selection: lex (d2,idx), order-
// independent, ties = lowest index = lax.top_k (r9-r11-verified).
// ===========================================================================
#define NSLAB 32
#define GLO   -4.0f
#define GCS    0.25f
#define GINV   4.0f

__device__ __forceinline__ float readlane_f(float v, int l) {
  return __int_as_float(__builtin_amdgcn_readlane(__float_as_int(v), l));
}
__device__ __forceinline__ int clampi(int v, int lo, int hi) {
  return v < lo ? lo : (v > hi ? hi : v);
}

__global__ __launch_bounds__(64) void zero_slab(int* __restrict__ c) {
  const int i = threadIdx.x;
  if (i < 2*NSLAB) c[i] = 0;
}

__global__ __launch_bounds__(256) void count_slab(const float* __restrict__ xyz,
                                                  int* __restrict__ counts) {
  const int i = blockIdx.x*256 + threadIdx.x;   // 0..BN-1
  const float z = xyz[(size_t)i*3+2];
  const int b = i >> 13;
  const int sz = clampi((int)floorf((z - GLO)*GINV), 0, NSLAB-1);
  atomicAdd(&counts[b*NSLAB + sz], 1);
}

__global__ __launch_bounds__(64) void scan_slab(const int* __restrict__ counts,
                                                int* __restrict__ starts,
                                                int* __restrict__ cursor) {
  const int t = threadIdx.x;
  if (t < 2) {                      // serial 32-prefix per batch (trivial)
    const int* c = counts + t*NSLAB;
    int* s  = starts + t*(NSLAB+1);
    int* cu = cursor + t*NSLAB;
    int acc = 0;
    for (int j = 0; j < NSLAB; ++j) { s[j] = acc; cu[j] = acc; acc += c[j]; }
    s[NSLAB] = acc;                 // = 8192
  }
}

__global__ __launch_bounds__(256) void scatter_slab(const float* __restrict__ xyz,
    int* __restrict__ cursor, float4* __restrict__ pts4, int* __restrict__ pidx) {
  const int i = blockIdx.x*256 + threadIdx.x;
  const float x = xyz[(size_t)i*3+0], y = xyz[(size_t)i*3+1], z = xyz[(size_t)i*3+2];
  const int b = i >> 13;
  const int sz = clampi((int)floorf((z - GLO)*GINV), 0, NSLAB-1);
  const float sq = __fadd_rn(__fadd_rn(__fmul_rn(x,x), __fmul_rn(y,y)),
                             __fmul_rn(z,z));
  const int slot = atomicAdd(&cursor[b*NSLAB + sz], 1);
  pts4[b*NPT + slot] = make_float4(x+x, y+y, z+z, sq);
  pidx[b*NPT + slot] = i & (NPT-1);   // within-batch index
}

// one wave per query; top-16 distributed over lanes 0..15, ascending lex
__global__ __launch_bounds__(256) void knn_query_kernel(const float* __restrict__ xyz,
    const int* __restrict__ starts, const float4* __restrict__ pts4,
    const int* __restrict__ pidx, int* __restrict__ knn_out) {
  const int tid = threadIdx.x, lane = tid & 63, wave = tid >> 6;
  const int p = blockIdx.x*4 + wave;
  const int b = p >> 13;
  const float qx = xyz[(size_t)p*3+0], qy = xyz[(size_t)p*3+1], qz = xyz[(size_t)p*3+2];
  const float qsq = __fadd_rn(__fadd_rn(__fmul_rn(qx,qx), __fmul_rn(qy,qy)),
                              __fmul_rn(qz,qz));
  const int cz = clampi((int)floorf((qz - GLO)*GINV), 0, NSLAB-1);
  const int*    sb = starts + b*(NSLAB+1);
  const float4* pb = pts4 + (size_t)b*NPT;
  const int*    ib = pidx + (size_t)b*NPT;

  float topd = INFINITY; int topi = 0x7fffffff;
  float tau  = INFINITY; int taui = 0x7fffffff;

  auto insert_cands = [&](float d2, int di) {
    unsigned long long m = __ballot((d2 < tau) | (d2 == tau && di < taui));
    while (m) {
      const int l = (int)__builtin_ctzll(m);
      const float dn  = readlane_f(d2, l);
      const int   dni = __builtin_amdgcn_readlane(di, l);
      const float my  = topd; const int myi = topi;
      float ab  = __shfl_up(my, 1);
      int   abi = __shfl_up(myi, 1);
      if (lane == 0) { ab = -INFINITY; abi = -1; }
      const bool ge = (dn < my) | (dn == my && dni < myi);
      const bool gt = (dn < ab) | (dn == ab && dni < abi);
      topd = ge ? (gt ? ab  : dn ) : my;
      topi = ge ? (gt ? abi : dni) : myi;
      tau  = readlane_f(topd, 15);
      taui = __builtin_amdgcn_readlane(topi, 15);
      m &= (m - 1);
      if (m) m &= __ballot((d2 < tau) | (d2 == tau && di < taui));
    }
  };
  auto proc_range = [&](int beg, int end) {   // coalesced 64-wide chunks
    for (int c0 = beg; c0 < end; c0 += 64) {
      const int ci = c0 + lane;
      float d2 = INFINITY; int di = 0x7fffffff;
      if (ci < end) {
        const float4 cd = pb[ci];
        const float dot2 = __fadd_rn(__fadd_rn(__fmul_rn(qx,cd.x),
                                               __fmul_rn(qy,cd.y)),
                                     __fmul_rn(qz,cd.z));
        d2 = __fsub_rn(__fadd_rn(qsq, cd.w), dot2);
        di = ib[ci];
      }
      insert_cands(d2, di);
    }
  };

  // initial window: slabs [cz-2, cz+2] — one contiguous range
  int lo = clampi(cz-2, 0, NSLAB-1);
  int hi = clampi(cz+2, 0, NSLAB-1);
  proc_range(sb[lo], sb[hi+1]);

  // widen tighter side until margin^2 > tau or everything scanned
  for (;;) {
    const float mlo = (lo == 0)       ? 3e38f
                      : (qz - (GLO + (float)lo*GCS) - 1e-5f);
    const float mhi = (hi == NSLAB-1) ? 3e38f
                      : ((GLO + (float)(hi+1)*GCS) - qz - 1e-5f);
    float mm = fminf(mlo, mhi);
    mm = fmaxf(mm, 0.f);
    if (mm*mm > tau) break;
    if (lo == 0 && hi == NSLAB-1) break;   // all 8192 scanned — exact
    if (mlo <= mhi) { --lo; proc_range(sb[lo], sb[lo+1]); }
    else            { ++hi; proc_range(sb[hi], sb[hi+1]); }
  }

  if (lane < KNN_K) knn_out[(size_t)p*KNN_K + lane] = topi;
}

// ---------------------------------------------------------------------------
// float4-component extract (u is compile-time constant in unrolled loops)
// ---------------------------------------------------------------------------
__device__ __forceinline__ float f4c(const float4 v, int u) {
  return u == 0 ? v.x : u == 1 ? v.y : u == 2 ? v.z : v.w;
}

// ---------------------------------------------------------------------------
// Kernel 2: fused Q/K/V projection, 4 rows/thread, 16 rows/block.
// (unchanged from r13)
// ---------------------------------------------------------------------------
#define QKV_ROWS 16

__global__ __launch_bounds__(128) void qkv_kernel(const float* __restrict__ x,
    const float* __restrict__ Wq, const float* __restrict__ bq,
    const float* __restrict__ Wk, const float* __restrict__ bk,
    const float* __restrict__ Wv, const float* __restrict__ bv,
    float* __restrict__ q, float* __restrict__ k, float* __restrict__ v) {
  __shared__ float xs[QKV_ROWS*DIMC];   // 8 KB
  const int tid = threadIdx.x;
  const int rowbase = blockIdx.x * QKV_ROWS;
  {
    float4* xs4 = (float4*)xs;
    const float4* src4 = (const float4*)(x + (size_t)rowbase*DIMC);
    for (int i = tid; i < QKV_ROWS*DIMC/4; i += 128) xs4[i] = src4[i];
  }
  __syncthreads();

  const int cg = tid & 31, rg = tid >> 5;   // rg 0..3
  const int c0 = cg * 4;
  float4 aq[4], ak[4], av[4];
  {
    const float4 bq4 = *(const float4*)&bq[c0];
    const float4 bk4 = *(const float4*)&bk[c0];
    const float4 bv4 = *(const float4*)&bv[c0];
#pragma unroll
    for (int i = 0; i < 4; ++i) { aq[i] = bq4; ak[i] = bk4; av[i] = bv4; }
  }

  for (int kk = 0; kk < DIMC; kk += 4) {
    float4 xr[4];
#pragma unroll
    for (int i = 0; i < 4; ++i)
      xr[i] = *(const float4*)&xs[(rg + 4*i)*DIMC + kk];
#pragma unroll
    for (int u = 0; u < 4; ++u) {
      const float4 wq = *(const float4*)&Wq[(size_t)(kk+u)*DIMC + c0];
      const float4 wk = *(const float4*)&Wk[(size_t)(kk+u)*DIMC + c0];
      const float4 wv = *(const float4*)&Wv[(size_t)(kk+u)*DIMC + c0];
#pragma unroll
      for (int i = 0; i < 4; ++i) {
        const float xv = f4c(xr[i], u);
        aq[i].x = fmaf(xv, wq.x, aq[i].x); aq[i].y = fmaf(xv, wq.y, aq[i].y);
        aq[i].z = fmaf(xv, wq.z, aq[i].z); aq[i].w = fmaf(xv, wq.w, aq[i].w);
        ak[i].x = fmaf(xv, wk.x, ak[i].x); ak[i].y = fmaf(xv, wk.y, ak[i].y);
        ak[i].z = fmaf(xv, wk.z, ak[i].z); ak[i].w = fmaf(xv, wk.w, ak[i].w);
        av[i].x = fmaf(xv, wv.x, av[i].x); av[i].y = fmaf(xv, wv.y, av[i].y);
        av[i].z = fmaf(xv, wv.z, av[i].z); av[i].w = fmaf(xv, wv.w, av[i].w);
      }
    }
  }

#pragma unroll
  for (int i = 0; i < 4; ++i) {
    const size_t rr = (size_t)(rowbase + rg + 4*i)*DIMC + c0;
    *(float4*)&q[rr] = aq[i];
    *(float4*)&k[rr] = ak[i];
    *(float4*)&v[rr] = av[i];
  }
}

// ---------------------------------------------------------------------------
// DPP ring-rotate move (VALU, no DS pipe): lane i of each 16-lane row reads
// lane (i+N)%16. Ring all-reduce with N=1,2,4,8 covers all 16 lanes.
// ---------------------------------------------------------------------------
template <int CTRL>
__device__ __forceinline__ float dppf(float x) {
  return __int_as_float(__builtin_amdgcn_update_dpp(
      __float_as_int(x), __float_as_int(x), CTRL, 0xF, 0xF, false));
}
#define ROR1 0x121
#define ROR2 0x122
#define ROR4 0x124
#define ROR8 0x128

// ---------------------------------------------------------------------------
// Kernel 3: gather + bias MLP + attention. ONE WAVE PER POINT. (unchanged)
// ---------------------------------------------------------------------------
__global__ __launch_bounds__(256) void attn_kernel(const float* __restrict__ xyz,
    const int* __restrict__ knn, const float* __restrict__ qb,
    const float* __restrict__ kb, const float* __restrict__ vb,
    const float* __restrict__ W1, const float* __restrict__ b1,
    const float* __restrict__ W2, const float* __restrict__ b2,
    float* __restrict__ ao) {
  __shared__ float sw[4][NH][KNN_K];
  __shared__ int   sn[4][KNN_K];
  const int tid  = threadIdx.x;
  const int wave = tid >> 6;
  const int lane = tid & 63;
  const int p = blockIdx.x * 4 + wave;
  const int b = p / NPT;
  const int h = lane >> 4;
  const int j = lane & 15;

  const int nj = knn[(size_t)p*KNN_K + j];
  if (h == 0) sn[wave][j] = nj;
  const size_t nn = (size_t)b*NPT + nj;

  // bias MLP for this lane's (h, j)
  const float qx0 = xyz[(size_t)p*3+0];
  const float qy0 = xyz[(size_t)p*3+1];
  const float qz0 = xyz[(size_t)p*3+2];
  const float rx = qx0 - xyz[nn*3+0];
  const float ry = qy0 - xyz[nn*3+1];
  const float rz = qz0 - xyz[nn*3+2];
  float bias = b2[h];
#pragma unroll 8
  for (int u = 0; u < HID; ++u) {
    float hv = rx*W1[0*HID+u] + ry*W1[1*HID+u] + rz*W1[2*HID+u] + b1[u];
    hv = hv > 0.f ? hv : 0.f;
    bias = fmaf(hv, W2[u*NH + h], bias);
  }

  // score: q[p,h,:] · k[nj,h,:]  (32 channels, 8x float4 each side)
  const float* qrow = qb + (size_t)p*DIMC + h*32;
  const float* krow = kb + nn*DIMC + h*32;
  float s = 0.f;
#pragma unroll
  for (int u = 0; u < 32; u += 4) {
    const float4 qv = *(const float4*)(qrow + u);
    const float4 kv = *(const float4*)(krow + u);
    s = fmaf(qv.x, kv.x, s); s = fmaf(qv.y, kv.y, s);
    s = fmaf(qv.z, kv.z, s); s = fmaf(qv.w, kv.w, s);
  }
  s = s * 0.17677669529663689f + bias;   // 1/sqrt(32)

  // softmax over the 16-lane j-group: DPP ring all-reduce (max, then sum)
  float m = s;
  m = fmaxf(m, dppf<ROR1>(m));
  m = fmaxf(m, dppf<ROR2>(m));
  m = fmaxf(m, dppf<ROR4>(m));
  m = fmaxf(m, dppf<ROR8>(m));
  const float e = expf(s - m);
  float ssum = e;
  ssum += dppf<ROR1>(ssum);
  ssum += dppf<ROR2>(ssum);
  ssum += dppf<ROR4>(ssum);
  ssum += dppf<ROR8>(ssum);
  sw[wave][h][j] = e / ssum;

  __syncthreads();

  // phase B: lane = channel d0 (and d0+64); weighted sum of v rows
  const int d0 = lane;
  const int hA = d0 >> 5;              // head of channel d0 (0 or 1)
  float out0 = 0.f, out1 = 0.f;
  const float* vbase = vb + (size_t)b*NPT*DIMC;
#pragma unroll 4
  for (int j2 = 0; j2 < KNN_K; ++j2) {
    const int n = sn[wave][j2];
    const float wA = sw[wave][hA][j2];
    const float wB = sw[wave][2+hA][j2];
    const float* vrow = vbase + (size_t)n*DIMC;
    out0 = fmaf(wA, vrow[d0],    out0);
    out1 = fmaf(wB, vrow[64+d0], out1);
  }
  ao[(size_t)p*DIMC + d0]      = out0;
  ao[(size_t)p*DIMC + 64 + d0] = out1;
}

// ---------------------------------------------------------------------------
// Kernel 4: output projection, 4 rows/thread, 16 rows/block, IN-PLACE on
// d_out. (unchanged from r13)
// ---------------------------------------------------------------------------
__global__ __launch_bounds__(128) void proj_kernel(float* __restrict__ inout,
    const float* __restrict__ Wo, const float* __restrict__ bo) {
  __shared__ float xs[QKV_ROWS*DIMC];   // 8 KB
  const int tid = threadIdx.x;
  const int rowbase = blockIdx.x * QKV_ROWS;
  {
    float4* xs4 = (float4*)xs;
    const float4* src4 = (const float4*)(inout + (size_t)rowbase*DIMC);
    for (int i = tid; i < QKV_ROWS*DIMC/4; i += 128) xs4[i] = src4[i];
  }
  __syncthreads();

  const int cg = tid & 31, rg = tid >> 5;   // rg 0..3
  const int c0 = cg * 4;
  float4 a[4];
  {
    const float4 bo4 = *(const float4*)&bo[c0];
#pragma unroll
    for (int i = 0; i < 4; ++i) a[i] = bo4;
  }

  for (int kk = 0; kk < DIMC; kk += 4) {
    float4 xr[4];
#pragma unroll
    for (int i = 0; i < 4; ++i)
      xr[i] = *(const float4*)&xs[(rg + 4*i)*DIMC + kk];
#pragma unroll
    for (int u = 0; u < 4; ++u) {
      const float4 w = *(const float4*)&Wo[(size_t)(kk+u)*DIMC + c0];
#pragma unroll
      for (int i = 0; i < 4; ++i) {
        const float xv = f4c(xr[i], u);
        a[i].x = fmaf(xv, w.x, a[i].x); a[i].y = fmaf(xv, w.y, a[i].y);
        a[i].z = fmaf(xv, w.z, a[i].z); a[i].w = fmaf(xv, w.w, a[i].w);
      }
    }
  }

#pragma unroll
  for (int i = 0; i < 4; ++i)
    *(float4*)&inout[(size_t)(rowbase + rg + 4*i)*DIMC + c0] = a[i];
}

// ---------------------------------------------------------------------------
extern "C" void kernel_launch(void* const* d_in, const int* in_sizes, int n_in,
                              void* d_out, int out_size, void* d_ws, size_t ws_size,
                              hipStream_t stream) {
  const float* x   = (const float*)d_in[0];
  const float* xyz = (const float*)d_in[1];
  const float* Wq  = (const float*)d_in[2];
  const float* bq  = (const float*)d_in[3];
  const float* Wk  = (const float*)d_in[4];
  const float* bk  = (const float*)d_in[5];
  const float* Wv  = (const float*)d_in[6];
  const float* bv  = (const float*)d_in[7];
  const float* Wo  = (const float*)d_in[8];
  const float* bo  = (const float*)d_in[9];
  const float* W1  = (const float*)d_in[10];
  const float* b1  = (const float*)d_in[11];
  const float* W2  = (const float*)d_in[12];
  const float* b2  = (const float*)d_in[13];
  float* out = (float*)d_out;

  // workspace layout (bytes):
  //   [0,1MB)     knn idx
  //   [1MB,9MB)   q  — slab-build arrays live here transiently (dead before
  //                    qkv_kernel writes q; stream order guarantees safety)
  //   [9MB,17MB)  k
  //   [17MB,25MB) v
  char* ws = (char*)d_ws;
  int*    knn    = (int*)ws;
  char*   g      = ws + (1u<<20);
  int*    counts = (int*)g;                       // 2*32 ints
  int*    starts = (int*)(g + 1024);              // 2*33 ints
  int*    cursor = (int*)(g + 2048);              // 2*32 ints
  float4* pts4   = (float4*)(g + 4096);           // 256 KB
  int*    pidx   = (int*)(g + 4096 + 256*1024);   //  64 KB
  float*  q      = (float*)(ws + (size_t)(1u<<20));
  float*  k      = (float*)(ws + (size_t)9*(1u<<20));
  float*  v      = (float*)(ws + (size_t)17*(1u<<20));

  hipLaunchKernelGGL(zero_slab,    dim3(1), dim3(64), 0, stream, counts);
  hipLaunchKernelGGL(count_slab,   dim3(BN/256), dim3(256), 0, stream, xyz, counts);
  hipLaunchKernelGGL(scan_slab,    dim3(1), dim3(64), 0, stream, counts, starts, cursor);
  hipLaunchKernelGGL(scatter_slab, dim3(BN/256), dim3(256), 0, stream, xyz, cursor, pts4, pidx);
  hipLaunchKernelGGL(knn_query_kernel, dim3(BN/4), dim3(256), 0, stream,
                     xyz, starts, pts4, pidx, knn);
  hipLaunchKernelGGL(qkv_kernel, dim3(BN/QKV_ROWS), dim3(128), 0, stream,
                     x, Wq, bq, Wk, bk, Wv, bv, q, k, v);
  hipLaunchKernelGGL(attn_kernel, dim3(BN/4), dim3(256), 0, stream,
                     xyz, knn, q, k, v, W1, b1, W2, b2, out);
  hipLaunchKernelGGL(proj_kernel, dim3(BN/QKV_ROWS), dim3(128), 0, stream,
                     out, Wo, bo);
}

// Round 17
// 188.196 us; speedup vs baseline: 1.5956x; 1.5956x over previous
//
#include <hip/hip_runtime.h>
#include <hip/hip_bf16.h>
#include <math.h>

#define BATCH 2
#define NPT   8192
#define DIMC  128
#define NH    4
#define KNN_K 16
#define HID   32
#define BN    (BATCH*NPT)   // 16384

// ---------------------------------------------------------------------------
// Fused Kernel 1: KNN (r13 full scan, proven 107 µs) ∥ QKV (r5 2-row body,
// proven) via block-range split. The two are data-independent; fusing them
// overlaps qkv's VALU/memory work into knn's idle issue slots (knn is 82%
// VALU-busy). g%3==2 -> qkv block (1024), else knn block (2048); grid is
// EXACTLY KNNB+QKVB=3072 (r15 had 3584 — OOB, caught in review before it
// ever ran). Both bodies are instruction-identical to their proven
// versions -> bit-identical results. LDS: union (knn 16 KB / qkv 8 KB).
// ---------------------------------------------------------------------------
#define TILE 1024
#define QPW  2
#define NWV  4
#define KNNB (BN/(NWV*QPW))      // 2048
#define QKVB (BN/16)             // 1024 (16 rows/block, 2 rows/thread)

__device__ __forceinline__ float readlane_f(float v, int l) {
  return __int_as_float(__builtin_amdgcn_readlane(__float_as_int(v), l));
}
// DPP row_shr:1 — lane i reads lane i-1 within its 16-lane row (VALU pipe).
__device__ __forceinline__ float dpp_shr1_f(float x) {
  return __int_as_float(__builtin_amdgcn_update_dpp(
      __float_as_int(x), __float_as_int(x), 0x111, 0xF, 0xF, false));
}
__device__ __forceinline__ int dpp_shr1_i(int x) {
  return __builtin_amdgcn_update_dpp(x, x, 0x111, 0xF, 0xF, false);
}
__device__ __forceinline__ float f4c(const float4 v, int u) {
  return u == 0 ? v.x : u == 1 ? v.y : u == 2 ? v.z : v.w;
}

__global__ __launch_bounds__(256) void knnqkv_kernel(
    const float* __restrict__ xyz, int* __restrict__ knn_out,
    const float* __restrict__ x,
    const float* __restrict__ Wq, const float* __restrict__ bq,
    const float* __restrict__ Wk, const float* __restrict__ bk,
    const float* __restrict__ Wv, const float* __restrict__ bv,
    float* __restrict__ q, float* __restrict__ k, float* __restrict__ v) {
  __shared__ float4 sbuf[TILE];   // 16 KB, shared by both paths
  const int g   = blockIdx.x;
  const int tid = threadIdx.x;

  if (g % 3 != 2) {
    // =================== KNN path (r13 body, 2048 blocks) ===================
    const int kb_  = (g/3)*2 + (g%3);
    const int lane = tid & 63;
    const int wave = tid >> 6;
    const int qbase = kb_ * (NWV*QPW) + wave * QPW;
    const int b = qbase / NPT;

    float qx[QPW], qy[QPW], qz[QPW], qsq[QPW];
    float topd[QPW]; int topi[QPW]; float tau[QPW];
#pragma unroll
    for (int qi = 0; qi < QPW; ++qi) {
      const int gg = qbase + qi;
      qx[qi] = xyz[(size_t)gg*3+0];
      qy[qi] = xyz[(size_t)gg*3+1];
      qz[qi] = xyz[(size_t)gg*3+2];
      qsq[qi] = __fadd_rn(__fadd_rn(__fmul_rn(qx[qi],qx[qi]),
                                    __fmul_rn(qy[qi],qy[qi])),
                          __fmul_rn(qz[qi],qz[qi]));
      topd[qi] = 3e38f; topi[qi] = 0; tau[qi] = 3e38f;
    }

    for (int t = 0; t < NPT/TILE; ++t) {
      __syncthreads();
      const float* src = xyz + (size_t)(b*NPT + t*TILE)*3;
      for (int i = tid; i < TILE; i += 256) {
        const float xx = src[i*3+0], yy = src[i*3+1], zz = src[i*3+2];
        const float sq = __fadd_rn(__fadd_rn(__fmul_rn(xx,xx), __fmul_rn(yy,yy)),
                                   __fmul_rn(zz,zz));
        sbuf[i] = make_float4(xx+xx, yy+yy, zz+zz, sq);
      }
      __syncthreads();

      for (int c = 0; c < TILE/64; ++c) {
        const float4 cd = sbuf[c*64 + lane];
        const int cbase = t*TILE + c*64;
#pragma unroll
        for (int qi = 0; qi < QPW; ++qi) {
          float dot2 = __fadd_rn(__fadd_rn(__fmul_rn(qx[qi],cd.x),
                                           __fmul_rn(qy[qi],cd.y)),
                                 __fmul_rn(qz[qi],cd.z));
          float d2 = __fsub_rn(__fadd_rn(qsq[qi], cd.w), dot2);
          unsigned long long m = __ballot(d2 < tau[qi]);
          while (m) {
            const int l = (int)__builtin_ctzll(m);
            const float dn = readlane_f(d2, l);
            const int   ni_ = cbase + l;
            const float my  = topd[qi];
            const int   myi = topi[qi];
            float ab  = dpp_shr1_f(my);
            int   abi = dpp_shr1_i(myi);
            if (lane == 0) ab = -3e38f;
            const bool ge = dn < my;
            const bool gt = dn < ab;
            topd[qi] = ge ? (gt ? ab  : dn ) : my;
            topi[qi] = ge ? (gt ? abi : ni_) : myi;
            tau[qi] = readlane_f(topd[qi], 15);
            m &= (m - 1);
            if (m) m &= __ballot(d2 < tau[qi]);
          }
        }
      }
    }

#pragma unroll
    for (int qi = 0; qi < QPW; ++qi) {
      if (lane < KNN_K) knn_out[(size_t)(qbase + qi)*KNN_K + lane] = topi[qi];
    }
  } else {
    // =================== QKV path (r5 body, 1024 blocks) ===================
    float* xs = (float*)sbuf;       // 16 rows x 128 = 8 KB
    const int qb_ = g/3;
    const int rowbase = qb_ * 16;
    {
      float4* xs4 = (float4*)xs;
      const float4* src4 = (const float4*)(x + (size_t)rowbase*DIMC);
      for (int i = tid; i < 16*DIMC/4; i += 256) xs4[i] = src4[i];
    }
    __syncthreads();

    const int cg = tid & 31, rg = tid >> 5;
    const int c0 = cg * 4;
    float4 aq0 = *(const float4*)&bq[c0], aq1 = aq0;
    float4 ak0 = *(const float4*)&bk[c0], ak1 = ak0;
    float4 av0 = *(const float4*)&bv[c0], av1 = av0;

    for (int kk = 0; kk < DIMC; kk += 4) {
      const float4 xa = *(const float4*)&xs[rg*DIMC + kk];
      const float4 xb = *(const float4*)&xs[(rg+8)*DIMC + kk];
#pragma unroll
      for (int u = 0; u < 4; ++u) {
        const float4 wq = *(const float4*)&Wq[(size_t)(kk+u)*DIMC + c0];
        const float4 wk = *(const float4*)&Wk[(size_t)(kk+u)*DIMC + c0];
        const float4 wv = *(const float4*)&Wv[(size_t)(kk+u)*DIMC + c0];
        const float xau = f4c(xa, u), xbu = f4c(xb, u);
        aq0.x = fmaf(xau, wq.x, aq0.x); aq0.y = fmaf(xau, wq.y, aq0.y);
        aq0.z = fmaf(xau, wq.z, aq0.z); aq0.w = fmaf(xau, wq.w, aq0.w);
        aq1.x = fmaf(xbu, wq.x, aq1.x); aq1.y = fmaf(xbu, wq.y, aq1.y);
        aq1.z = fmaf(xbu, wq.z, aq1.z); aq1.w = fmaf(xbu, wq.w, aq1.w);
        ak0.x = fmaf(xau, wk.x, ak0.x); ak0.y = fmaf(xau, wk.y, ak0.y);
        ak0.z = fmaf(xau, wk.z, ak0.z); ak0.w = fmaf(xau, wk.w, ak0.w);
        ak1.x = fmaf(xbu, wk.x, ak1.x); ak1.y = fmaf(xbu, wk.y, ak1.y);
        ak1.z = fmaf(xbu, wk.z, ak1.z); ak1.w = fmaf(xbu, wk.w, ak1.w);
        av0.x = fmaf(xau, wv.x, av0.x); av0.y = fmaf(xau, wv.y, av0.y);
        av0.z = fmaf(xau, wv.z, av0.z); av0.w = fmaf(xau, wv.w, av0.w);
        av1.x = fmaf(xbu, wv.x, av1.x); av1.y = fmaf(xbu, wv.y, av1.y);
        av1.z = fmaf(xbu, wv.z, av1.z); av1.w = fmaf(xbu, wv.w, av1.w);
      }
    }

    const size_t r0 = (size_t)(rowbase + rg)*DIMC + c0;
    const size_t r1 = (size_t)(rowbase + rg + 8)*DIMC + c0;
    *(float4*)&q[r0] = aq0; *(float4*)&q[r1] = aq1;
    *(float4*)&k[r0] = ak0; *(float4*)&k[r1] = ak1;
    *(float4*)&v[r0] = av0; *(float4*)&v[r1] = av1;
  }
}

// ---------------------------------------------------------------------------
// DPP ring-rotate move (VALU, no DS pipe): lane i of each 16-lane row reads
// lane (i+N)%16. Ring all-reduce with N=1,2,4,8 covers all 16 lanes.
// ---------------------------------------------------------------------------
template <int CTRL>
__device__ __forceinline__ float dppf(float x) {
  return __int_as_float(__builtin_amdgcn_update_dpp(
      __float_as_int(x), __float_as_int(x), CTRL, 0xF, 0xF, false));
}
#define ROR1 0x121
#define ROR2 0x122
#define ROR4 0x124
#define ROR8 0x128

// ---------------------------------------------------------------------------
// Kernel 2: gather + bias MLP + attention. ONE WAVE PER POINT. (unchanged)
// ---------------------------------------------------------------------------
__global__ __launch_bounds__(256) void attn_kernel(const float* __restrict__ xyz,
    const int* __restrict__ knn, const float* __restrict__ qb,
    const float* __restrict__ kb, const float* __restrict__ vb,
    const float* __restrict__ W1, const float* __restrict__ b1,
    const float* __restrict__ W2, const float* __restrict__ b2,
    float* __restrict__ ao) {
  __shared__ float sw[4][NH][KNN_K];
  __shared__ int   sn[4][KNN_K];
  const int tid  = threadIdx.x;
  const int wave = tid >> 6;
  const int lane = tid & 63;
  const int p = blockIdx.x * 4 + wave;
  const int b = p / NPT;
  const int h = lane >> 4;
  const int j = lane & 15;

  const int nj = knn[(size_t)p*KNN_K + j];
  if (h == 0) sn[wave][j] = nj;
  const size_t nn = (size_t)b*NPT + nj;

  // bias MLP for this lane's (h, j)
  const float qx0 = xyz[(size_t)p*3+0];
  const float qy0 = xyz[(size_t)p*3+1];
  const float qz0 = xyz[(size_t)p*3+2];
  const float rx = qx0 - xyz[nn*3+0];
  const float ry = qy0 - xyz[nn*3+1];
  const float rz = qz0 - xyz[nn*3+2];
  float bias = b2[h];
#pragma unroll 8
  for (int u = 0; u < HID; ++u) {
    float hv = rx*W1[0*HID+u] + ry*W1[1*HID+u] + rz*W1[2*HID+u] + b1[u];
    hv = hv > 0.f ? hv : 0.f;
    bias = fmaf(hv, W2[u*NH + h], bias);
  }

  // score: q[p,h,:] · k[nj,h,:]  (32 channels, 8x float4 each side)
  const float* qrow = qb + (size_t)p*DIMC + h*32;
  const float* krow = kb + nn*DIMC + h*32;
  float s = 0.f;
#pragma unroll
  for (int u = 0; u < 32; u += 4) {
    const float4 qv = *(const float4*)(qrow + u);
    const float4 kv = *(const float4*)(krow + u);
    s = fmaf(qv.x, kv.x, s); s = fmaf(qv.y, kv.y, s);
    s = fmaf(qv.z, kv.z, s); s = fmaf(qv.w, kv.w, s);
  }
  s = s * 0.17677669529663689f + bias;   // 1/sqrt(32)

  // softmax over the 16-lane j-group: DPP ring all-reduce (max, then sum)
  float m = s;
  m = fmaxf(m, dppf<ROR1>(m));
  m = fmaxf(m, dppf<ROR2>(m));
  m = fmaxf(m, dppf<ROR4>(m));
  m = fmaxf(m, dppf<ROR8>(m));
  const float e = expf(s - m);
  float ssum = e;
  ssum += dppf<ROR1>(ssum);
  ssum += dppf<ROR2>(ssum);
  ssum += dppf<ROR4>(ssum);
  ssum += dppf<ROR8>(ssum);
  sw[wave][h][j] = e / ssum;

  __syncthreads();

  // phase B: lane = channel d0 (and d0+64); weighted sum of v rows
  const int d0 = lane;
  const int hA = d0 >> 5;              // head of channel d0 (0 or 1)
  float out0 = 0.f, out1 = 0.f;
  const float* vbase = vb + (size_t)b*NPT*DIMC;
#pragma unroll 4
  for (int j2 = 0; j2 < KNN_K; ++j2) {
    const int n = sn[wave][j2];
    const float wA = sw[wave][hA][j2];
    const float wB = sw[wave][2+hA][j2];
    const float* vrow = vbase + (size_t)n*DIMC;
    out0 = fmaf(wA, vrow[d0],    out0);
    out1 = fmaf(wB, vrow[64+d0], out1);
  }
  ao[(size_t)p*DIMC + d0]      = out0;
  ao[(size_t)p*DIMC + 64 + d0] = out1;
}

// ---------------------------------------------------------------------------
// Kernel 3: output projection, 4 rows/thread, 16 rows/block, IN-PLACE on
// d_out. (unchanged from r13)
// ---------------------------------------------------------------------------
#define PROJ_ROWS 16

__global__ __launch_bounds__(128) void proj_kernel(float* __restrict__ inout,
    const float* __restrict__ Wo, const float* __restrict__ bo) {
  __shared__ float xs[PROJ_ROWS*DIMC];   // 8 KB
  const int tid = threadIdx.x;
  const int rowbase = blockIdx.x * PROJ_ROWS;
  {
    float4* xs4 = (float4*)xs;
    const float4* src4 = (const float4*)(inout + (size_t)rowbase*DIMC);
    for (int i = tid; i < PROJ_ROWS*DIMC/4; i += 128) xs4[i] = src4[i];
  }
  __syncthreads();

  const int cg = tid & 31, rg = tid >> 5;   // rg 0..3
  const int c0 = cg * 4;
  float4 a[4];
  {
    const float4 bo4 = *(const float4*)&bo[c0];
#pragma unroll
    for (int i = 0; i < 4; ++i) a[i] = bo4;
  }

  for (int kk = 0; kk < DIMC; kk += 4) {
    float4 xr[4];
#pragma unroll
    for (int i = 0; i < 4; ++i)
      xr[i] = *(const float4*)&xs[(rg + 4*i)*DIMC + kk];
#pragma unroll
    for (int u = 0; u < 4; ++u) {
      const float4 w = *(const float4*)&Wo[(size_t)(kk+u)*DIMC + c0];
#pragma unroll
      for (int i = 0; i < 4; ++i) {
        const float xv = f4c(xr[i], u);
        a[i].x = fmaf(xv, w.x, a[i].x); a[i].y = fmaf(xv, w.y, a[i].y);
        a[i].z = fmaf(xv, w.z, a[i].z); a[i].w = fmaf(xv, w.w, a[i].w);
      }
    }
  }

#pragma unroll
  for (int i = 0; i < 4; ++i)
    *(float4*)&inout[(size_t)(rowbase + rg + 4*i)*DIMC + c0] = a[i];
}

// ---------------------------------------------------------------------------
extern "C" void kernel_launch(void* const* d_in, const int* in_sizes, int n_in,
                              void* d_out, int out_size, void* d_ws, size_t ws_size,
                              hipStream_t stream) {
  const float* x   = (const float*)d_in[0];
  const float* xyz = (const float*)d_in[1];
  const float* Wq  = (const float*)d_in[2];
  const float* bq  = (const float*)d_in[3];
  const float* Wk  = (const float*)d_in[4];
  const float* bk  = (const float*)d_in[5];
  const float* Wv  = (const float*)d_in[6];
  const float* bv  = (const float*)d_in[7];
  const float* Wo  = (const float*)d_in[8];
  const float* bo  = (const float*)d_in[9];
  const float* W1  = (const float*)d_in[10];
  const float* b1  = (const float*)d_in[11];
  const float* W2  = (const float*)d_in[12];
  const float* b2  = (const float*)d_in[13];
  float* out = (float*)d_out;

  // workspace layout (bytes): knn idx 1MB | q 8MB | k 8MB | v 8MB  => 25MB
  char* ws = (char*)d_ws;
  int*   knn = (int*)ws;
  float* q   = (float*)(ws + (size_t)(1u<<20));
  float* k   = (float*)(ws + (size_t)9*(1u<<20));
  float* v   = (float*)(ws + (size_t)17*(1u<<20));

  // grid = KNNB + QKVB = 3072 exactly (2 knn + 1 qkv per g-triple)
  hipLaunchKernelGGL(knnqkv_kernel, dim3(KNNB + QKVB), dim3(256), 0, stream,
                     xyz, knn, x, Wq, bq, Wk, bk, Wv, bv, q, k, v);
  hipLaunchKernelGGL(attn_kernel, dim3(BN/4), dim3(256), 0, stream,
                     xyz, knn, q, k, v, W1, b1, W2, b2, out);
  hipLaunchKernelGGL(proj_kernel, dim3(BN/PROJ_ROWS), dim3(128), 0, stream,
                     out, Wo, bo);
}